// Round 15
// baseline (179.914 us; speedup 1.0000x reference)
//
#include <hip/hip_runtime.h>
#include <hip/hip_bf16.h>
#include <math.h>

#define B_   16
#define N_   4096
#define D_   768
#define H_   12
#define L_   2
#define K_   16
#define S_   17
#define M_   272          // B_*S_
#define BN_  65536        // B_*N_

typedef __bf16 bf16x8 __attribute__((ext_vector_type(8)));
typedef float  f32x4  __attribute__((ext_vector_type(4)));

static __device__ __forceinline__ unsigned short f2bf(float f) {
    __bf16 h = (__bf16)f;
    return __builtin_bit_cast(unsigned short, h);
}
static __device__ __forceinline__ float bf2f(unsigned short u) {
    __bf16 h = __builtin_bit_cast(__bf16, u);
    return (float)h;
}
static __device__ __forceinline__ unsigned long long umax64(unsigned long long a, unsigned long long b) {
    return a > b ? a : b;
}
static __device__ __forceinline__ void split4(const float4& v, ushort4& hh, ushort4& ll) {
    hh.x = f2bf(v.x); ll.x = f2bf(v.x - bf2f(hh.x));
    hh.y = f2bf(v.y); ll.y = f2bf(v.y - bf2f(hh.y));
    hh.z = f2bf(v.z); ll.z = f2bf(v.z - bf2f(hh.z));
    hh.w = f2bf(v.w); ll.w = f2bf(v.w - bf2f(hh.w));
}

// ===========================================================================
// Gate v2-64: SAME barrier/staging structure as frozen v2 (verified r7/9/12/14)
// but 64 instances/block (grid 1024) for 2x occupancy — each wave owns 16
// rows, mi-dimension removed. Per-instance math order unchanged.
// ===========================================================================
__global__ __launch_bounds__(256)
void gate_kernel(const float* __restrict__ x, const float* __restrict__ gln_g,
                 const float* __restrict__ gln_b, const float* __restrict__ gW1,
                 const float* __restrict__ gb1, const float* __restrict__ gW2,
                 const float* __restrict__ gb2, float* __restrict__ wbuf)
{
    __shared__ __align__(16) char WS[16384];          // Wh 8KB | Wl 8KB
    __shared__ float mS[64], rS[64], A1s[64], A2s[64];
    __shared__ float rA1[256], rA2[256];
    char* WhB = WS;
    char* WlB = WS + 8192;

    const int t   = threadIdx.x;
    const int bn0 = blockIdx.x * 64;
    const int wv  = t >> 6, la = t & 63, fr = la & 15, fq = la >> 4;

    const int te = t >> 2;            // 0..63 (e row)
    const int tq = (t & 3) * 16;      // col group
    const float* wrow = gW1 + (size_t)te * D_ + tq;

    const float* arow = x + (size_t)(bn0 + wv * 16 + fr) * D_;

    f32x4 acc[4];
    #pragma unroll
    for (int ni = 0; ni < 4; ++ni) {
        f32x4 z = {0.f, 0.f, 0.f, 0.f};
        acc[ni] = z;
    }

    float sx0 = 0.f, sxx0 = 0.f;
    float a1p = 0.f, a2p = 0.f;

    float4 pa[2][2];
    #pragma unroll
    for (int ks = 0; ks < 2; ++ks) {
        pa[ks][0] = *(const float4*)(arow + ks * 32 + fq * 8);
        pa[ks][1] = *(const float4*)(arow + ks * 32 + fq * 8 + 4);
    }

    for (int kt = 0; kt < 12; ++kt) {
        __syncthreads();
        {
            const float* wsrc = wrow + kt * 64;
            const float* gsrc = gln_g + kt * 64 + tq;
            const float* bsrc = gln_b + kt * 64 + tq;
            #pragma unroll
            for (int j = 0; j < 4; ++j) {
                float4 w4 = *(const float4*)(wsrc + j * 4);
                float4 g4 = *(const float4*)(gsrc + j * 4);
                float4 b4 = *(const float4*)(bsrc + j * 4);
                float4 wt;
                wt.x = w4.x * g4.x; wt.y = w4.y * g4.y;
                wt.z = w4.z * g4.z; wt.w = w4.w * g4.w;
                a1p += wt.x + wt.y + wt.z + wt.w;
                a2p += b4.x * w4.x + b4.y * w4.y + b4.z * w4.z + b4.w * w4.w;
                ushort4 hh, ll;
                split4(wt, hh, ll);
                int byte = (te * 128 + (tq + j * 4) * 2) ^ ((te & 7) << 4);
                *(ushort4*)(WhB + byte) = hh;
                *(ushort4*)(WlB + byte) = ll;
            }
        }
        __syncthreads();

        float4 na[2][2];
        if (kt < 11) {
            const float* ar = arow + (kt + 1) * 64;
            #pragma unroll
            for (int ks = 0; ks < 2; ++ks) {
                na[ks][0] = *(const float4*)(ar + ks * 32 + fq * 8);
                na[ks][1] = *(const float4*)(ar + ks * 32 + fq * 8 + 4);
            }
        }

        #pragma unroll
        for (int ks = 0; ks < 2; ++ks) {
            bf16x8 ah, al;
            {
                float v[8];
                v[0] = pa[ks][0].x; v[1] = pa[ks][0].y;
                v[2] = pa[ks][0].z; v[3] = pa[ks][0].w;
                v[4] = pa[ks][1].x; v[5] = pa[ks][1].y;
                v[6] = pa[ks][1].z; v[7] = pa[ks][1].w;
                #pragma unroll
                for (int i = 0; i < 8; ++i) {
                    sx0 += v[i]; sxx0 += v[i] * v[i];
                    __bf16 h = (__bf16)v[i];
                    ah[i] = h;
                    al[i] = (__bf16)(v[i] - (float)h);
                }
            }
            bf16x8 bh[4], bl[4];
            const int kb = ks * 64 + fq * 16;
            #pragma unroll
            for (int ni = 0; ni < 4; ++ni) {
                int e    = ni * 16 + fr;
                int byte = (e * 128 + kb) ^ ((e & 7) << 4);
                bh[ni] = *(const bf16x8*)(WhB + byte);
                bl[ni] = *(const bf16x8*)(WlB + byte);
            }
            #pragma unroll
            for (int ni = 0; ni < 4; ++ni) {
                acc[ni] = __builtin_amdgcn_mfma_f32_16x16x32_bf16(ah, bh[ni], acc[ni], 0, 0, 0);
                acc[ni] = __builtin_amdgcn_mfma_f32_16x16x32_bf16(ah, bl[ni], acc[ni], 0, 0, 0);
                acc[ni] = __builtin_amdgcn_mfma_f32_16x16x32_bf16(al, bh[ni], acc[ni], 0, 0, 0);
            }
        }
        if (kt < 11) {
            #pragma unroll
            for (int ks = 0; ks < 2; ++ks) {
                pa[ks][0] = na[ks][0];
                pa[ks][1] = na[ks][1];
            }
        }
    }

    __syncthreads();
    {
        float s0 = sx0, q0 = sxx0;
        s0 += __shfl_xor(s0, 16); s0 += __shfl_xor(s0, 32);
        q0 += __shfl_xor(q0, 16); q0 += __shfl_xor(q0, 32);
        if (fq == 0) {
            int r0 = wv * 16 + fr;
            float m0 = s0 * (1.0f / D_);
            mS[r0] = m0;
            rS[r0] = rsqrtf(q0 * (1.0f / D_) - m0 * m0 + 1e-5f);
        }
    }
    rA1[te * 4 + (t & 3)] = a1p;
    rA2[te * 4 + (t & 3)] = a2p;
    __syncthreads();
    if (t < 64) {
        A1s[t] = rA1[t * 4] + rA1[t * 4 + 1] + rA1[t * 4 + 2] + rA1[t * 4 + 3];
        A2s[t] = rA2[t * 4] + rA2[t * 4 + 1] + rA2[t * 4 + 2] + rA2[t * 4 + 3];
    }
    __syncthreads();

    float w2v[4], a1v[4], a2b[4];
    #pragma unroll
    for (int ni = 0; ni < 4; ++ni) {
        int e = ni * 16 + fr;
        w2v[ni] = gW2[e];
        a1v[ni] = A1s[e];
        a2b[ni] = A2s[e] + gb1[e];
    }
    float gb2v = gb2[0];

    #pragma unroll
    for (int j = 0; j < 4; ++j) {
        int inst = wv * 16 + fq * 4 + j;
        float m = mS[inst], rs = rS[inst];
        float tp = 0.f;
        #pragma unroll
        for (int ni = 0; ni < 4; ++ni) {
            float h  = rs * (acc[ni][j] - m * a1v[ni]) + a2b[ni];
            float hg = 0.5f * h * (1.0f + erff(h * 0.70710678118654752f));
            tp = fmaf(hg, w2v[ni], tp);
        }
        tp += __shfl_xor(tp, 1);
        tp += __shfl_xor(tp, 2);
        tp += __shfl_xor(tp, 4);
        tp += __shfl_xor(tp, 8);
        if (fr == 0) wbuf[bn0 + inst] = 1.0f / (1.0f + expf(-(tp + gb2v)));
    }
}

// ===========================================================================
// Top-16 per bag (verified r14): 256 threads, 16 keys/thread in regs
// ===========================================================================
__global__ __launch_bounds__(256)
void topk_kernel(const float* __restrict__ wbuf, float* __restrict__ topv,
                 int* __restrict__ topi)
{
    __shared__ unsigned long long SB[16];
    const int b = blockIdx.x, t = threadIdx.x;
    const int la = t & 63, wid = t >> 6;

    unsigned long long key[16];
    #pragma unroll
    for (int j = 0; j < 16; ++j) {
        int i = t + 256 * j;
        float v = wbuf[(size_t)b * N_ + i];
        key[j] = ((unsigned long long)__float_as_uint(v) << 12) | (unsigned long long)(4095 - i);
    }
    for (int k = 0; k < K_; ++k) {
        unsigned long long kk = key[0];
        #pragma unroll
        for (int j = 1; j < 16; ++j) kk = umax64(kk, key[j]);
        #pragma unroll
        for (int o = 1; o < 64; o <<= 1) kk = umax64(kk, (unsigned long long)__shfl_xor(kk, o));
        if (la == 0) SB[wid] = kk;
        __syncthreads();
        if (t == 0) {
            unsigned long long m = umax64(umax64(SB[0], SB[1]), umax64(SB[2], SB[3]));
            SB[8] = m;
            int wi = 4095 - (int)(m & 0xfffULL);
            topv[b * K_ + k] = __uint_as_float((unsigned int)(m >> 12));
            topi[b * K_ + k] = wi;
        }
        __syncthreads();
        unsigned long long m = SB[8];
        int wi = 4095 - (int)(m & 0xfffULL);
        #pragma unroll
        for (int j = 0; j < 16; ++j)
            if (wi == t + 256 * j) key[j] = 0ULL;
        __syncthreads();
    }
}

// ===========================================================================
// Build one seq row per block (verified r14): gather+weight, LN -> z0
// ===========================================================================
__global__ __launch_bounds__(256)
void build_kernel(const float* __restrict__ x, const float* __restrict__ cls,
                  const float* __restrict__ ln_g, const float* __restrict__ ln_b,
                  const float* __restrict__ topv, const int* __restrict__ topi,
                  float* __restrict__ z0)
{
    __shared__ float sm[8];
    const int r = blockIdx.x, b = r / S_, s = r % S_;
    const int t = threadIdx.x;
    float v[3];
    if (s == 0) {
        #pragma unroll
        for (int p = 0; p < 3; ++p) v[p] = cls[t + 256 * p];
    } else {
        int   idx = topi[b * K_ + s - 1];
        float tv  = topv[b * K_ + s - 1];
        const float* row = &x[((size_t)b * N_ + idx) * D_];
        #pragma unroll
        for (int p = 0; p < 3; ++p) v[p] = row[t + 256 * p] * tv;
    }
    float sum = 0.f, ss = 0.f;
    #pragma unroll
    for (int p = 0; p < 3; ++p) { sum += v[p]; ss += v[p] * v[p]; }
    #pragma unroll
    for (int o = 32; o; o >>= 1) { sum += __shfl_down(sum, o); ss += __shfl_down(ss, o); }
    int wid = t >> 6, la = t & 63;
    if (la == 0) { sm[wid * 2] = sum; sm[wid * 2 + 1] = ss; }
    __syncthreads();
    sum = sm[0] + sm[2] + sm[4] + sm[6];
    ss  = sm[1] + sm[3] + sm[5] + sm[7];
    float m = sum * (1.0f / D_), rstd = rsqrtf(ss * (1.0f / D_) - m * m + 1e-5f);
    #pragma unroll
    for (int p = 0; p < 3; ++p) {
        int d = t + 256 * p;
        z0[(size_t)r * D_ + d] = (v[p] - m) * rstd * ln_g[d] + ln_b[d];
    }
}

// ===========================================================================
// MFMA GEMM (verified): C[m][n] = sum_k A[m][k]*W[n][k] + bias[n]
// ===========================================================================
__global__ __launch_bounds__(256)
void gemm_mfma(const float* __restrict__ A, const float* __restrict__ W,
               const float* __restrict__ bias, float* __restrict__ C, int N)
{
    __shared__ __align__(16) char SB[32768];
    char* AhB = SB;
    char* AlB = SB + 8192;
    char* WhB = SB + 16384;
    char* WlB = SB + 24576;

    const int t  = threadIdx.x;
    const int m0 = blockIdx.x * 64, n0 = blockIdx.y * 64;

    const int sr = t >> 2;
    const int sc = (t & 3) * 16;
    const int gm = m0 + sr;
    const bool aok = (gm < M_);
    const float* asrc = A + (size_t)gm * D_ + sc;
    const float* wsrc = W + (size_t)(n0 + sr) * D_ + sc;

    const int wv = t >> 6, la = t & 63;
    const int fr = la & 15, fq = la >> 4;
    const int wm = (wv & 1) * 32, wn = (wv >> 1) * 32;

    f32x4 acc[2][2];
    #pragma unroll
    for (int mi = 0; mi < 2; ++mi)
        #pragma unroll
        for (int ni = 0; ni < 2; ++ni) {
            f32x4 z = {0.f, 0.f, 0.f, 0.f};
            acc[mi][ni] = z;
        }

    float4 pa[4], pw[4];
    #pragma unroll
    for (int q = 0; q < 4; ++q) {
        pa[q] = aok ? *(const float4*)(asrc + q * 4) : make_float4(0.f, 0.f, 0.f, 0.f);
        pw[q] = *(const float4*)(wsrc + q * 4);
    }

    const int abyte0 = sr * 128 + sc * 2;
    const int asw0   = (abyte0)      ^ ((sr & 7) << 4);
    const int asw1   = (abyte0 + 16) ^ ((sr & 7) << 4);

    for (int kt = 0; kt < 12; ++kt) {
        __syncthreads();
        {
            ushort4 hh[4], ll[4];
            #pragma unroll
            for (int q = 0; q < 4; ++q) split4(pa[q], hh[q], ll[q]);
            *(ushort4*)(AhB + asw0)     = hh[0];
            *(ushort4*)(AhB + asw0 + 8) = hh[1];
            *(ushort4*)(AhB + asw1)     = hh[2];
            *(ushort4*)(AhB + asw1 + 8) = hh[3];
            *(ushort4*)(AlB + asw0)     = ll[0];
            *(ushort4*)(AlB + asw0 + 8) = ll[1];
            *(ushort4*)(AlB + asw1)     = ll[2];
            *(ushort4*)(AlB + asw1 + 8) = ll[3];
            #pragma unroll
            for (int q = 0; q < 4; ++q) split4(pw[q], hh[q], ll[q]);
            *(ushort4*)(WhB + asw0)     = hh[0];
            *(ushort4*)(WhB + asw0 + 8) = hh[1];
            *(ushort4*)(WhB + asw1)     = hh[2];
            *(ushort4*)(WhB + asw1 + 8) = hh[3];
            *(ushort4*)(WlB + asw0)     = ll[0];
            *(ushort4*)(WlB + asw0 + 8) = ll[1];
            *(ushort4*)(WlB + asw1)     = ll[2];
            *(ushort4*)(WlB + asw1 + 8) = ll[3];
        }
        __syncthreads();
        if (kt < 11) {
            const float* an  = asrc + (kt + 1) * 64;
            const float* wn2 = wsrc + (kt + 1) * 64;
            #pragma unroll
            for (int q = 0; q < 4; ++q) {
                pa[q] = aok ? *(const float4*)(an + q * 4) : make_float4(0.f, 0.f, 0.f, 0.f);
                pw[q] = *(const float4*)(wn2 + q * 4);
            }
        }
        #pragma unroll
        for (int ks = 0; ks < 2; ++ks) {
            int kb = ks * 64 + fq * 16;
            bf16x8 ah[2], al[2], bh[2], bl[2];
            #pragma unroll
            for (int mi = 0; mi < 2; ++mi) {
                int r    = wm + mi * 16 + fr;
                int byte = (r * 128 + kb) ^ ((r & 7) << 4);
                ah[mi] = *(const bf16x8*)(AhB + byte);
                al[mi] = *(const bf16x8*)(AlB + byte);
            }
            #pragma unroll
            for (int ni = 0; ni < 2; ++ni) {
                int r    = wn + ni * 16 + fr;
                int byte = (r * 128 + kb) ^ ((r & 7) << 4);
                bh[ni] = *(const bf16x8*)(WhB + byte);
                bl[ni] = *(const bf16x8*)(WlB + byte);
            }
            #pragma unroll
            for (int mi = 0; mi < 2; ++mi)
                #pragma unroll
                for (int ni = 0; ni < 2; ++ni) {
                    acc[mi][ni] = __builtin_amdgcn_mfma_f32_16x16x32_bf16(ah[mi], bh[ni], acc[mi][ni], 0, 0, 0);
                    acc[mi][ni] = __builtin_amdgcn_mfma_f32_16x16x32_bf16(ah[mi], bl[ni], acc[mi][ni], 0, 0, 0);
                    acc[mi][ni] = __builtin_amdgcn_mfma_f32_16x16x32_bf16(al[mi], bh[ni], acc[mi][ni], 0, 0, 0);
                }
        }
    }

    #pragma unroll
    for (int mi = 0; mi < 2; ++mi) {
        #pragma unroll
        for (int j = 0; j < 4; ++j) {
            int m = m0 + wm + mi * 16 + fq * 4 + j;
            if (m < M_) {
                #pragma unroll
                for (int ni = 0; ni < 2; ++ni) {
                    int n = n0 + wn + ni * 16 + fr;
                    C[(size_t)m * N + n] = acc[mi][ni][j] + bias[n];
                }
            }
        }
    }
}

// ===========================================================================
// Attention layer-0 (verified): one block per (b,h)
// ===========================================================================
__global__ __launch_bounds__(256)
void attn_kernel(const float* __restrict__ qkvb, float* __restrict__ obuf)
{
    __shared__ __align__(16) float F[3 * S_ * 65 + S_ * 18];
    float* qs  = F;
    float* ks  = F + S_ * 65;
    float* vs  = F + 2 * S_ * 65;
    float* att = F + 3 * S_ * 65;
    const int bh = blockIdx.x, b = bh / H_, h = bh % H_;
    const int bq = b * S_;
    const int t = threadIdx.x;

    for (int idx = t; idx < S_ * 64; idx += 256) {
        int s = idx >> 6, d = idx & 63;
        size_t off = (size_t)(bq + s) * (3 * D_) + h * 64 + d;
        qs[s * 65 + d] = qkvb[off];
        ks[s * 65 + d] = qkvb[off + D_];
        vs[s * 65 + d] = qkvb[off + 2 * D_];
    }
    __syncthreads();
    for (int idx = t; idx < S_ * S_; idx += 256) {
        int i = idx / S_, j = idx % S_;
        float sdot = 0.f;
        #pragma unroll
        for (int d = 0; d < 64; ++d) sdot = fmaf(qs[i * 65 + d], ks[j * 65 + d], sdot);
        att[i * 18 + j] = sdot * 0.125f;
    }
    __syncthreads();
    if (t < S_) {
        float mx = -1e30f;
        for (int j = 0; j < S_; ++j) mx = fmaxf(mx, att[t * 18 + j]);
        float ssum = 0.f;
        for (int j = 0; j < S_; ++j) { float e = expf(att[t * 18 + j] - mx); att[t * 18 + j] = e; ssum += e; }
        float inv = 1.0f / ssum;
        for (int j = 0; j < S_; ++j) att[t * 18 + j] *= inv;
    }
    __syncthreads();
    for (int idx = t; idx < S_ * 64; idx += 256) {
        int i = idx >> 6, d = idx & 63;
        float s = 0.f;
        #pragma unroll
        for (int j = 0; j < S_; ++j) s = fmaf(att[i * 18 + j], vs[j * 65 + d], s);
        obuf[(size_t)(bq + i) * D_ + h * 64 + d] = s;
    }
}

// ===========================================================================
// Residual + LN -> abuf (verified)
// ===========================================================================
__global__ __launch_bounds__(256)
void resln_kernel(const float* __restrict__ z0, const float* __restrict__ projb,
                  const float* __restrict__ ln_g, const float* __restrict__ ln_b,
                  float* __restrict__ abuf)
{
    __shared__ float sm[8];
    const int r = blockIdx.x, t = threadIdx.x;
    float v[3];
    #pragma unroll
    for (int p = 0; p < 3; ++p) {
        int d = t + 256 * p;
        v[p] = z0[(size_t)r * D_ + d] + projb[(size_t)r * D_ + d];
    }
    float sum = 0.f, ss = 0.f;
    #pragma unroll
    for (int p = 0; p < 3; ++p) { sum += v[p]; ss += v[p] * v[p]; }
    #pragma unroll
    for (int o = 32; o; o >>= 1) { sum += __shfl_down(sum, o); ss += __shfl_down(ss, o); }
    int wid = t >> 6, la = t & 63;
    if (la == 0) { sm[wid * 2] = sum; sm[wid * 2 + 1] = ss; }
    __syncthreads();
    sum = sm[0] + sm[2] + sm[4] + sm[6];
    ss  = sm[1] + sm[3] + sm[5] + sm[7];
    float m = sum * (1.0f / D_), rstd = rsqrtf(ss * (1.0f / D_) - m * m + 1e-5f);
    #pragma unroll
    for (int p = 0; p < 3; ++p) {
        int d = t + 256 * p;
        abuf[(size_t)r * D_ + d] = (v[p] - m) * rstd * ln_g[d] + ln_b[d];
    }
}

// ===========================================================================
// Layer-1 attention, query row 0 only; writes compact o1c[b][768]
// ===========================================================================
__global__ __launch_bounds__(128)
void attn1r0_kernel(const float* __restrict__ qkvb, float* __restrict__ o1c)
{
    __shared__ float q0[64], kv[S_][65], vv[S_][64], p[S_], red[2];
    const int bh = blockIdx.x, b = bh / H_, h = bh % H_;
    const int t = threadIdx.x;
    const size_t rowbase = (size_t)(b * S_) * (3 * D_) + h * 64;

    for (int idx = t; idx < S_ * 64; idx += 128) {
        int s = idx >> 6, d = idx & 63;
        kv[s][d] = qkvb[rowbase + (size_t)s * (3 * D_) + D_ + d];
        vv[s][d] = qkvb[rowbase + (size_t)s * (3 * D_) + 2 * D_ + d];
    }
    if (t < 64) q0[t] = qkvb[rowbase + t];
    __syncthreads();
    if (t < S_) {
        float sdot = 0.f;
        #pragma unroll
        for (int d = 0; d < 64; ++d) sdot = fmaf(q0[d], kv[t][d], sdot);
        p[t] = sdot * 0.125f;
    }
    __syncthreads();
    if (t == 0) {
        float mx = -1e30f;
        for (int j = 0; j < S_; ++j) mx = fmaxf(mx, p[j]);
        red[0] = mx;
    }
    __syncthreads();
    if (t < S_) p[t] = expf(p[t] - red[0]);
    __syncthreads();
    if (t == 0) {
        float s = 0.f;
        for (int j = 0; j < S_; ++j) s += p[j];
        red[1] = 1.0f / s;
    }
    __syncthreads();
    if (t < 64) {
        float s = 0.f;
        #pragma unroll
        for (int j = 0; j < S_; ++j) s = fmaf(p[j], vv[j][t], s);
        o1c[(size_t)b * D_ + h * 64 + t] = s * red[1];
    }
}

// ===========================================================================
// Layer-1 projection, M=16: projc[16][768]
// ===========================================================================
__global__ __launch_bounds__(256)
void proj1c_kernel(const float* __restrict__ A,   // o1c [16][768]
                   const float* __restrict__ W,   // Wo1 [768][768]
                   const float* __restrict__ bias,
                   float* __restrict__ C)         // projc [16][768]
{
    __shared__ __align__(16) char SB[20480];
    char* AhB = SB;            // [16][64] bf16 = 2KB
    char* AlB = SB + 2048;
    char* WhB = SB + 4096;     // [64][64] = 8KB
    char* WlB = SB + 12288;

    const int t  = threadIdx.x;
    const int n0 = blockIdx.x * 64;

    const int ar = t >> 4;            // 0..15
    const int ac = (t & 15) * 4;      // col group of 4
    const int sr = t >> 2;            // 0..63 (W row)
    const int sc = (t & 3) * 16;

    const int wv = t >> 6, la = t & 63;
    const int fr = la & 15, fq = la >> 4;

    f32x4 acc = {0.f, 0.f, 0.f, 0.f};

    float4 pa = *(const float4*)(A + (size_t)ar * D_ + ac);
    float4 pw[4];
    #pragma unroll
    for (int q = 0; q < 4; ++q)
        pw[q] = *(const float4*)(W + (size_t)(n0 + sr) * D_ + sc + q * 4);

    for (int kt = 0; kt < 12; ++kt) {
        __syncthreads();
        {
            ushort4 hh, ll;
            split4(pa, hh, ll);
            int byte = (ar * 128 + ac * 2) ^ ((ar & 7) << 4);
            *(ushort4*)(AhB + byte) = hh;
            *(ushort4*)(AlB + byte) = ll;
            ushort4 whh[4], wll[4];
            #pragma unroll
            for (int q = 0; q < 4; ++q) split4(pw[q], whh[q], wll[q]);
            int wb0 = (sr * 128 + sc * 2) ^ ((sr & 7) << 4);
            int wb1 = (sr * 128 + sc * 2 + 16) ^ ((sr & 7) << 4);
            *(ushort4*)(WhB + wb0)     = whh[0];
            *(ushort4*)(WhB + wb0 + 8) = whh[1];
            *(ushort4*)(WhB + wb1)     = whh[2];
            *(ushort4*)(WhB + wb1 + 8) = whh[3];
            *(ushort4*)(WlB + wb0)     = wll[0];
            *(ushort4*)(WlB + wb0 + 8) = wll[1];
            *(ushort4*)(WlB + wb1)     = wll[2];
            *(ushort4*)(WlB + wb1 + 8) = wll[3];
        }
        __syncthreads();
        if (kt < 11) {
            pa = *(const float4*)(A + (size_t)ar * D_ + (kt + 1) * 64 + ac);
            #pragma unroll
            for (int q = 0; q < 4; ++q)
                pw[q] = *(const float4*)(W + (size_t)(n0 + sr) * D_ + (kt + 1) * 64 + sc + q * 4);
        }
        #pragma unroll
        for (int ks = 0; ks < 2; ++ks) {
            int kb = ks * 64 + fq * 16;
            int abyte = (fr * 128 + kb) ^ ((fr & 7) << 4);
            bf16x8 ah = *(const bf16x8*)(AhB + abyte);
            bf16x8 al = *(const bf16x8*)(AlB + abyte);
            int r = wv * 16 + fr;
            int wbyte = (r * 128 + kb) ^ ((r & 7) << 4);
            bf16x8 bh = *(const bf16x8*)(WhB + wbyte);
            bf16x8 bl = *(const bf16x8*)(WlB + wbyte);
            acc = __builtin_amdgcn_mfma_f32_16x16x32_bf16(ah, bh, acc, 0, 0, 0);
            acc = __builtin_amdgcn_mfma_f32_16x16x32_bf16(ah, bl, acc, 0, 0, 0);
            acc = __builtin_amdgcn_mfma_f32_16x16x32_bf16(al, bh, acc, 0, 0, 0);
        }
    }

    #pragma unroll
    for (int j = 0; j < 4; ++j) {
        int m = fq * 4 + j;              // 0..15
        int n = n0 + wv * 16 + fr;
        C[(size_t)m * D_ + n] = acc[j] + bias[n];
    }
}

// ===========================================================================
// Final output: out[b] = LN(z0[b*17] + projc[b])
// ===========================================================================
__global__ __launch_bounds__(256)
void outln_kernel(const float* __restrict__ z0, const float* __restrict__ projc,
                  const float* __restrict__ ln_g, const float* __restrict__ ln_b,
                  float* __restrict__ out)
{
    __shared__ float sm[8];
    const int b = blockIdx.x, t = threadIdx.x;
    float v[3];
    #pragma unroll
    for (int p = 0; p < 3; ++p) {
        int d = t + 256 * p;
        v[p] = z0[((size_t)b * S_) * D_ + d] + projc[(size_t)b * D_ + d];
    }
    float sum = 0.f, ss = 0.f;
    #pragma unroll
    for (int p = 0; p < 3; ++p) { sum += v[p]; ss += v[p] * v[p]; }
    #pragma unroll
    for (int o = 32; o; o >>= 1) { sum += __shfl_down(sum, o); ss += __shfl_down(ss, o); }
    int wid = t >> 6, la = t & 63;
    if (la == 0) { sm[wid * 2] = sum; sm[wid * 2 + 1] = ss; }
    __syncthreads();
    sum = sm[0] + sm[2] + sm[4] + sm[6];
    ss  = sm[1] + sm[3] + sm[5] + sm[7];
    float m = sum * (1.0f / D_), rstd = rsqrtf(ss * (1.0f / D_) - m * m + 1e-5f);
    #pragma unroll
    for (int p = 0; p < 3; ++p) {
        int d = t + 256 * p;
        out[(size_t)b * D_ + d] = (v[p] - m) * rstd * ln_g[d] + ln_b[d];
    }
}

// ---------------------------------------------------------------------------
extern "C" void kernel_launch(void* const* d_in, const int* in_sizes, int n_in,
                              void* d_out, int out_size, void* d_ws, size_t ws_size,
                              hipStream_t stream)
{
    const float* x     = (const float*)d_in[0];
    const float* cls   = (const float*)d_in[1];
    const float* ln_g  = (const float*)d_in[2];
    const float* ln_b  = (const float*)d_in[3];
    const float* gln_g = (const float*)d_in[4];
    const float* gln_b = (const float*)d_in[5];
    const float* gW1   = (const float*)d_in[6];
    const float* gb1   = (const float*)d_in[7];
    const float* gW2   = (const float*)d_in[8];
    const float* gb2   = (const float*)d_in[9];
    const float* Wqkv  = (const float*)d_in[10];
    const float* bqkv  = (const float*)d_in[11];
    const float* Wo    = (const float*)d_in[12];
    const float* bo    = (const float*)d_in[13];
    float* out = (float*)d_out;

    float* ws    = (float*)d_ws;
    float* wbuf  = ws;                          // 65536
    float* z0    = ws + BN_;                    // 208896
    float* abuf  = z0 + (size_t)M_ * D_;        // 208896
    float* qkvb  = abuf + (size_t)M_ * D_;      // 626688
    float* obuf  = qkvb + (size_t)M_ * 3 * D_;  // 208896 (layer1: o1c = first 16*768)
    float* projb = obuf + (size_t)M_ * D_;      // 208896 (layer1: projc = first 16*768)
    float* topv  = projb + (size_t)M_ * D_;     // 256
    int*   topi  = (int*)(topv + 256);          // 256

    gate_kernel<<<BN_ / 64, 256, 0, stream>>>(x, gln_g, gln_b, gW1, gb1, gW2, gb2, wbuf);
    topk_kernel<<<B_, 256, 0, stream>>>(wbuf, topv, topi);
    build_kernel<<<M_, 256, 0, stream>>>(x, cls, ln_g, ln_b, topv, topi, z0);

    // layer 0 (full)
    gemm_mfma<<<dim3(5, 36), 256, 0, stream>>>(z0, Wqkv, bqkv, qkvb, 3 * D_);
    attn_kernel<<<B_ * H_, 256, 0, stream>>>(qkvb, obuf);
    gemm_mfma<<<dim3(5, 12), 256, 0, stream>>>(obuf, Wo, bo, projb, D_);
    resln_kernel<<<M_, 256, 0, stream>>>(z0, projb, ln_g, ln_b, abuf);

    // layer 1 (trimmed to row s=0 outputs)
    gemm_mfma<<<dim3(5, 36), 256, 0, stream>>>(abuf, Wqkv + (size_t)3 * D_ * D_,
                                               bqkv + 3 * D_, qkvb, 3 * D_);
    attn1r0_kernel<<<B_ * H_, 128, 0, stream>>>(qkvb, obuf);
    proj1c_kernel<<<12, 256, 0, stream>>>(obuf, Wo + (size_t)D_ * D_, bo + D_, projb);
    outln_kernel<<<B_, 256, 0, stream>>>(z0, projb, ln_g, ln_b, out);
}

// Round 16
// 153.154 us; speedup vs baseline: 1.1747x; 1.1747x over previous
//
#include <hip/hip_runtime.h>
#include <hip/hip_bf16.h>
#include <math.h>

#define B_   16
#define N_   4096
#define D_   768
#define H_   12
#define L_   2
#define K_   16
#define S_   17
#define M_   272          // B_*S_
#define BN_  65536        // B_*N_

typedef __bf16 bf16x8 __attribute__((ext_vector_type(8)));
typedef float  f32x4  __attribute__((ext_vector_type(4)));

static __device__ __forceinline__ unsigned short f2bf(float f) {
    __bf16 h = (__bf16)f;
    return __builtin_bit_cast(unsigned short, h);
}
static __device__ __forceinline__ float bf2f(unsigned short u) {
    __bf16 h = __builtin_bit_cast(__bf16, u);
    return (float)h;
}
static __device__ __forceinline__ unsigned long long umax64(unsigned long long a, unsigned long long b) {
    return a > b ? a : b;
}
static __device__ __forceinline__ void split4(const float4& v, ushort4& hh, ushort4& ll) {
    hh.x = f2bf(v.x); ll.x = f2bf(v.x - bf2f(hh.x));
    hh.y = f2bf(v.y); ll.y = f2bf(v.y - bf2f(hh.y));
    hh.z = f2bf(v.z); ll.z = f2bf(v.z - bf2f(hh.z));
    hh.w = f2bf(v.w); ll.w = f2bf(v.w - bf2f(hh.w));
}

// ===========================================================================
// Gate v2 (FROZEN — verified rounds 7/9/12/14; the 128-row tiling is the
// optimum of {W-staging amortization x occupancy}: 64-row (r15) and pipeline
// restructures (r10/r11) all regressed or broke determinism).
// ===========================================================================
__global__ __launch_bounds__(256)
void gate_kernel(const float* __restrict__ x, const float* __restrict__ gln_g,
                 const float* __restrict__ gln_b, const float* __restrict__ gW1,
                 const float* __restrict__ gb1, const float* __restrict__ gW2,
                 const float* __restrict__ gb2, float* __restrict__ wbuf)
{
    __shared__ __align__(16) char WS[16384];          // Wh 8KB | Wl 8KB
    __shared__ float mS[128], rS[128], A1s[64], A2s[64];
    __shared__ float rA1[256], rA2[256];
    char* WhB = WS;
    char* WlB = WS + 8192;

    const int t   = threadIdx.x;
    const int bn0 = blockIdx.x * 128;
    const int wv  = t >> 6, la = t & 63, fr = la & 15, fq = la >> 4;

    const int te = t >> 2;            // 0..63 (e row)
    const int tq = (t & 3) * 16;      // col group
    const float* wrow = gW1 + (size_t)te * D_ + tq;

    const float* arow0 = x + (size_t)(bn0 + wv * 32 + fr) * D_;
    const float* arow1 = arow0 + (size_t)16 * D_;

    f32x4 acc[2][4];
    #pragma unroll
    for (int mi = 0; mi < 2; ++mi)
        #pragma unroll
        for (int ni = 0; ni < 4; ++ni) {
            f32x4 z = {0.f, 0.f, 0.f, 0.f};
            acc[mi][ni] = z;
        }

    float sx0 = 0.f, sxx0 = 0.f, sx1 = 0.f, sxx1 = 0.f;
    float a1p = 0.f, a2p = 0.f;

    float4 pa[2][2][2];
    #pragma unroll
    for (int mi = 0; mi < 2; ++mi) {
        const float* ar = mi ? arow1 : arow0;
        #pragma unroll
        for (int ks = 0; ks < 2; ++ks) {
            pa[mi][ks][0] = *(const float4*)(ar + ks * 32 + fq * 8);
            pa[mi][ks][1] = *(const float4*)(ar + ks * 32 + fq * 8 + 4);
        }
    }

    for (int kt = 0; kt < 12; ++kt) {
        __syncthreads();
        {
            const float* wsrc = wrow + kt * 64;
            const float* gsrc = gln_g + kt * 64 + tq;
            const float* bsrc = gln_b + kt * 64 + tq;
            #pragma unroll
            for (int j = 0; j < 4; ++j) {
                float4 w4 = *(const float4*)(wsrc + j * 4);
                float4 g4 = *(const float4*)(gsrc + j * 4);
                float4 b4 = *(const float4*)(bsrc + j * 4);
                float4 wt;
                wt.x = w4.x * g4.x; wt.y = w4.y * g4.y;
                wt.z = w4.z * g4.z; wt.w = w4.w * g4.w;
                a1p += wt.x + wt.y + wt.z + wt.w;
                a2p += b4.x * w4.x + b4.y * w4.y + b4.z * w4.z + b4.w * w4.w;
                ushort4 hh, ll;
                split4(wt, hh, ll);
                int byte = (te * 128 + (tq + j * 4) * 2) ^ ((te & 7) << 4);
                *(ushort4*)(WhB + byte) = hh;
                *(ushort4*)(WlB + byte) = ll;
            }
        }
        __syncthreads();

        float4 na[2][2][2];
        if (kt < 11) {
            #pragma unroll
            for (int mi = 0; mi < 2; ++mi) {
                const float* ar = (mi ? arow1 : arow0) + (kt + 1) * 64;
                #pragma unroll
                for (int ks = 0; ks < 2; ++ks) {
                    na[mi][ks][0] = *(const float4*)(ar + ks * 32 + fq * 8);
                    na[mi][ks][1] = *(const float4*)(ar + ks * 32 + fq * 8 + 4);
                }
            }
        }

        #pragma unroll
        for (int ks = 0; ks < 2; ++ks) {
            bf16x8 ah[2], al[2];
            #pragma unroll
            for (int mi = 0; mi < 2; ++mi) {
                float v[8];
                v[0] = pa[mi][ks][0].x; v[1] = pa[mi][ks][0].y;
                v[2] = pa[mi][ks][0].z; v[3] = pa[mi][ks][0].w;
                v[4] = pa[mi][ks][1].x; v[5] = pa[mi][ks][1].y;
                v[6] = pa[mi][ks][1].z; v[7] = pa[mi][ks][1].w;
                #pragma unroll
                for (int i = 0; i < 8; ++i) {
                    if (mi == 0) { sx0 += v[i]; sxx0 += v[i] * v[i]; }
                    else         { sx1 += v[i]; sxx1 += v[i] * v[i]; }
                    __bf16 h = (__bf16)v[i];
                    ah[mi][i] = h;
                    al[mi][i] = (__bf16)(v[i] - (float)h);
                }
            }
            bf16x8 bh[4], bl[4];
            const int kb = ks * 64 + fq * 16;
            #pragma unroll
            for (int ni = 0; ni < 4; ++ni) {
                int e    = ni * 16 + fr;
                int byte = (e * 128 + kb) ^ ((e & 7) << 4);
                bh[ni] = *(const bf16x8*)(WhB + byte);
                bl[ni] = *(const bf16x8*)(WlB + byte);
            }
            #pragma unroll
            for (int mi = 0; mi < 2; ++mi)
                #pragma unroll
                for (int ni = 0; ni < 4; ++ni) {
                    acc[mi][ni] = __builtin_amdgcn_mfma_f32_16x16x32_bf16(ah[mi], bh[ni], acc[mi][ni], 0, 0, 0);
                    acc[mi][ni] = __builtin_amdgcn_mfma_f32_16x16x32_bf16(ah[mi], bl[ni], acc[mi][ni], 0, 0, 0);
                    acc[mi][ni] = __builtin_amdgcn_mfma_f32_16x16x32_bf16(al[mi], bh[ni], acc[mi][ni], 0, 0, 0);
                }
        }
        if (kt < 11) {
            #pragma unroll
            for (int mi = 0; mi < 2; ++mi)
                #pragma unroll
                for (int ks = 0; ks < 2; ++ks) {
                    pa[mi][ks][0] = na[mi][ks][0];
                    pa[mi][ks][1] = na[mi][ks][1];
                }
        }
    }

    __syncthreads();
    {
        float s0 = sx0, q0 = sxx0, s1 = sx1, q1 = sxx1;
        s0 += __shfl_xor(s0, 16); s0 += __shfl_xor(s0, 32);
        q0 += __shfl_xor(q0, 16); q0 += __shfl_xor(q0, 32);
        s1 += __shfl_xor(s1, 16); s1 += __shfl_xor(s1, 32);
        q1 += __shfl_xor(q1, 16); q1 += __shfl_xor(q1, 32);
        if (fq == 0) {
            int r0 = wv * 32 + fr;
            float m0 = s0 * (1.0f / D_);
            mS[r0] = m0;
            rS[r0] = rsqrtf(q0 * (1.0f / D_) - m0 * m0 + 1e-5f);
            float m1 = s1 * (1.0f / D_);
            mS[r0 + 16] = m1;
            rS[r0 + 16] = rsqrtf(q1 * (1.0f / D_) - m1 * m1 + 1e-5f);
        }
    }
    rA1[te * 4 + (t & 3)] = a1p;
    rA2[te * 4 + (t & 3)] = a2p;
    __syncthreads();
    if (t < 64) {
        A1s[t] = rA1[t * 4] + rA1[t * 4 + 1] + rA1[t * 4 + 2] + rA1[t * 4 + 3];
        A2s[t] = rA2[t * 4] + rA2[t * 4 + 1] + rA2[t * 4 + 2] + rA2[t * 4 + 3];
    }
    __syncthreads();

    float w2v[4], a1v[4], a2b[4];
    #pragma unroll
    for (int ni = 0; ni < 4; ++ni) {
        int e = ni * 16 + fr;
        w2v[ni] = gW2[e];
        a1v[ni] = A1s[e];
        a2b[ni] = A2s[e] + gb1[e];
    }
    float gb2v = gb2[0];

    #pragma unroll
    for (int mi = 0; mi < 2; ++mi) {
        #pragma unroll
        for (int j = 0; j < 4; ++j) {
            int inst = wv * 32 + mi * 16 + fq * 4 + j;
            float m = mS[inst], rs = rS[inst];
            float tp = 0.f;
            #pragma unroll
            for (int ni = 0; ni < 4; ++ni) {
                float h  = rs * (acc[mi][ni][j] - m * a1v[ni]) + a2b[ni];
                float hg = 0.5f * h * (1.0f + erff(h * 0.70710678118654752f));
                tp = fmaf(hg, w2v[ni], tp);
            }
            tp += __shfl_xor(tp, 1);
            tp += __shfl_xor(tp, 2);
            tp += __shfl_xor(tp, 4);
            tp += __shfl_xor(tp, 8);
            if (fr == 0) wbuf[bn0 + inst] = 1.0f / (1.0f + expf(-(tp + gb2v)));
        }
    }
}

// ===========================================================================
// Top-16 per bag (verified r14): 256 threads, 16 keys/thread in regs
// ===========================================================================
__global__ __launch_bounds__(256)
void topk_kernel(const float* __restrict__ wbuf, float* __restrict__ topv,
                 int* __restrict__ topi)
{
    __shared__ unsigned long long SB[16];
    const int b = blockIdx.x, t = threadIdx.x;
    const int la = t & 63, wid = t >> 6;

    unsigned long long key[16];
    #pragma unroll
    for (int j = 0; j < 16; ++j) {
        int i = t + 256 * j;
        float v = wbuf[(size_t)b * N_ + i];
        key[j] = ((unsigned long long)__float_as_uint(v) << 12) | (unsigned long long)(4095 - i);
    }
    for (int k = 0; k < K_; ++k) {
        unsigned long long kk = key[0];
        #pragma unroll
        for (int j = 1; j < 16; ++j) kk = umax64(kk, key[j]);
        #pragma unroll
        for (int o = 1; o < 64; o <<= 1) kk = umax64(kk, (unsigned long long)__shfl_xor(kk, o));
        if (la == 0) SB[wid] = kk;
        __syncthreads();
        if (t == 0) {
            unsigned long long m = umax64(umax64(SB[0], SB[1]), umax64(SB[2], SB[3]));
            SB[8] = m;
            int wi = 4095 - (int)(m & 0xfffULL);
            topv[b * K_ + k] = __uint_as_float((unsigned int)(m >> 12));
            topi[b * K_ + k] = wi;
        }
        __syncthreads();
        unsigned long long m = SB[8];
        int wi = 4095 - (int)(m & 0xfffULL);
        #pragma unroll
        for (int j = 0; j < 16; ++j)
            if (wi == t + 256 * j) key[j] = 0ULL;
        __syncthreads();
    }
}

// ===========================================================================
// Build one seq row per block (verified r14): gather+weight, LN -> z0
// ===========================================================================
__global__ __launch_bounds__(256)
void build_kernel(const float* __restrict__ x, const float* __restrict__ cls,
                  const float* __restrict__ ln_g, const float* __restrict__ ln_b,
                  const float* __restrict__ topv, const int* __restrict__ topi,
                  float* __restrict__ z0)
{
    __shared__ float sm[8];
    const int r = blockIdx.x, b = r / S_, s = r % S_;
    const int t = threadIdx.x;
    float v[3];
    if (s == 0) {
        #pragma unroll
        for (int p = 0; p < 3; ++p) v[p] = cls[t + 256 * p];
    } else {
        int   idx = topi[b * K_ + s - 1];
        float tv  = topv[b * K_ + s - 1];
        const float* row = &x[((size_t)b * N_ + idx) * D_];
        #pragma unroll
        for (int p = 0; p < 3; ++p) v[p] = row[t + 256 * p] * tv;
    }
    float sum = 0.f, ss = 0.f;
    #pragma unroll
    for (int p = 0; p < 3; ++p) { sum += v[p]; ss += v[p] * v[p]; }
    #pragma unroll
    for (int o = 32; o; o >>= 1) { sum += __shfl_down(sum, o); ss += __shfl_down(ss, o); }
    int wid = t >> 6, la = t & 63;
    if (la == 0) { sm[wid * 2] = sum; sm[wid * 2 + 1] = ss; }
    __syncthreads();
    sum = sm[0] + sm[2] + sm[4] + sm[6];
    ss  = sm[1] + sm[3] + sm[5] + sm[7];
    float m = sum * (1.0f / D_), rstd = rsqrtf(ss * (1.0f / D_) - m * m + 1e-5f);
    #pragma unroll
    for (int p = 0; p < 3; ++p) {
        int d = t + 256 * p;
        z0[(size_t)r * D_ + d] = (v[p] - m) * rstd * ln_g[d] + ln_b[d];
    }
}

// ===========================================================================
// MFMA GEMM (verified): C[m][n] = sum_k A[m][k]*W[n][k] + bias[n]
// ===========================================================================
__global__ __launch_bounds__(256)
void gemm_mfma(const float* __restrict__ A, const float* __restrict__ W,
               const float* __restrict__ bias, float* __restrict__ C, int N)
{
    __shared__ __align__(16) char SB[32768];
    char* AhB = SB;
    char* AlB = SB + 8192;
    char* WhB = SB + 16384;
    char* WlB = SB + 24576;

    const int t  = threadIdx.x;
    const int m0 = blockIdx.x * 64, n0 = blockIdx.y * 64;

    const int sr = t >> 2;
    const int sc = (t & 3) * 16;
    const int gm = m0 + sr;
    const bool aok = (gm < M_);
    const float* asrc = A + (size_t)gm * D_ + sc;
    const float* wsrc = W + (size_t)(n0 + sr) * D_ + sc;

    const int wv = t >> 6, la = t & 63;
    const int fr = la & 15, fq = la >> 4;
    const int wm = (wv & 1) * 32, wn = (wv >> 1) * 32;

    f32x4 acc[2][2];
    #pragma unroll
    for (int mi = 0; mi < 2; ++mi)
        #pragma unroll
        for (int ni = 0; ni < 2; ++ni) {
            f32x4 z = {0.f, 0.f, 0.f, 0.f};
            acc[mi][ni] = z;
        }

    float4 pa[4], pw[4];
    #pragma unroll
    for (int q = 0; q < 4; ++q) {
        pa[q] = aok ? *(const float4*)(asrc + q * 4) : make_float4(0.f, 0.f, 0.f, 0.f);
        pw[q] = *(const float4*)(wsrc + q * 4);
    }

    const int abyte0 = sr * 128 + sc * 2;
    const int asw0   = (abyte0)      ^ ((sr & 7) << 4);
    const int asw1   = (abyte0 + 16) ^ ((sr & 7) << 4);

    for (int kt = 0; kt < 12; ++kt) {
        __syncthreads();
        {
            ushort4 hh[4], ll[4];
            #pragma unroll
            for (int q = 0; q < 4; ++q) split4(pa[q], hh[q], ll[q]);
            *(ushort4*)(AhB + asw0)     = hh[0];
            *(ushort4*)(AhB + asw0 + 8) = hh[1];
            *(ushort4*)(AhB + asw1)     = hh[2];
            *(ushort4*)(AhB + asw1 + 8) = hh[3];
            *(ushort4*)(AlB + asw0)     = ll[0];
            *(ushort4*)(AlB + asw0 + 8) = ll[1];
            *(ushort4*)(AlB + asw1)     = ll[2];
            *(ushort4*)(AlB + asw1 + 8) = ll[3];
            #pragma unroll
            for (int q = 0; q < 4; ++q) split4(pw[q], hh[q], ll[q]);
            *(ushort4*)(WhB + asw0)     = hh[0];
            *(ushort4*)(WhB + asw0 + 8) = hh[1];
            *(ushort4*)(WhB + asw1)     = hh[2];
            *(ushort4*)(WhB + asw1 + 8) = hh[3];
            *(ushort4*)(WlB + asw0)     = ll[0];
            *(ushort4*)(WlB + asw0 + 8) = ll[1];
            *(ushort4*)(WlB + asw1)     = ll[2];
            *(ushort4*)(WlB + asw1 + 8) = ll[3];
        }
        __syncthreads();
        if (kt < 11) {
            const float* an  = asrc + (kt + 1) * 64;
            const float* wn2 = wsrc + (kt + 1) * 64;
            #pragma unroll
            for (int q = 0; q < 4; ++q) {
                pa[q] = aok ? *(const float4*)(an + q * 4) : make_float4(0.f, 0.f, 0.f, 0.f);
                pw[q] = *(const float4*)(wn2 + q * 4);
            }
        }
        #pragma unroll
        for (int ks = 0; ks < 2; ++ks) {
            int kb = ks * 64 + fq * 16;
            bf16x8 ah[2], al[2], bh[2], bl[2];
            #pragma unroll
            for (int mi = 0; mi < 2; ++mi) {
                int r    = wm + mi * 16 + fr;
                int byte = (r * 128 + kb) ^ ((r & 7) << 4);
                ah[mi] = *(const bf16x8*)(AhB + byte);
                al[mi] = *(const bf16x8*)(AlB + byte);
            }
            #pragma unroll
            for (int ni = 0; ni < 2; ++ni) {
                int r    = wn + ni * 16 + fr;
                int byte = (r * 128 + kb) ^ ((r & 7) << 4);
                bh[ni] = *(const bf16x8*)(WhB + byte);
                bl[ni] = *(const bf16x8*)(WlB + byte);
            }
            #pragma unroll
            for (int mi = 0; mi < 2; ++mi)
                #pragma unroll
                for (int ni = 0; ni < 2; ++ni) {
                    acc[mi][ni] = __builtin_amdgcn_mfma_f32_16x16x32_bf16(ah[mi], bh[ni], acc[mi][ni], 0, 0, 0);
                    acc[mi][ni] = __builtin_amdgcn_mfma_f32_16x16x32_bf16(ah[mi], bl[ni], acc[mi][ni], 0, 0, 0);
                    acc[mi][ni] = __builtin_amdgcn_mfma_f32_16x16x32_bf16(al[mi], bh[ni], acc[mi][ni], 0, 0, 0);
                }
        }
    }

    #pragma unroll
    for (int mi = 0; mi < 2; ++mi) {
        #pragma unroll
        for (int j = 0; j < 4; ++j) {
            int m = m0 + wm + mi * 16 + fq * 4 + j;
            if (m < M_) {
                #pragma unroll
                for (int ni = 0; ni < 2; ++ni) {
                    int n = n0 + wn + ni * 16 + fr;
                    C[(size_t)m * N + n] = acc[mi][ni][j] + bias[n];
                }
            }
        }
    }
}

// ===========================================================================
// Attention layer-0 (verified): one block per (b,h)
// ===========================================================================
__global__ __launch_bounds__(256)
void attn_kernel(const float* __restrict__ qkvb, float* __restrict__ obuf)
{
    __shared__ __align__(16) float F[3 * S_ * 65 + S_ * 18];
    float* qs  = F;
    float* ks  = F + S_ * 65;
    float* vs  = F + 2 * S_ * 65;
    float* att = F + 3 * S_ * 65;
    const int bh = blockIdx.x, b = bh / H_, h = bh % H_;
    const int bq = b * S_;
    const int t = threadIdx.x;

    for (int idx = t; idx < S_ * 64; idx += 256) {
        int s = idx >> 6, d = idx & 63;
        size_t off = (size_t)(bq + s) * (3 * D_) + h * 64 + d;
        qs[s * 65 + d] = qkvb[off];
        ks[s * 65 + d] = qkvb[off + D_];
        vs[s * 65 + d] = qkvb[off + 2 * D_];
    }
    __syncthreads();
    for (int idx = t; idx < S_ * S_; idx += 256) {
        int i = idx / S_, j = idx % S_;
        float sdot = 0.f;
        #pragma unroll
        for (int d = 0; d < 64; ++d) sdot = fmaf(qs[i * 65 + d], ks[j * 65 + d], sdot);
        att[i * 18 + j] = sdot * 0.125f;
    }
    __syncthreads();
    if (t < S_) {
        float mx = -1e30f;
        for (int j = 0; j < S_; ++j) mx = fmaxf(mx, att[t * 18 + j]);
        float ssum = 0.f;
        for (int j = 0; j < S_; ++j) { float e = expf(att[t * 18 + j] - mx); att[t * 18 + j] = e; ssum += e; }
        float inv = 1.0f / ssum;
        for (int j = 0; j < S_; ++j) att[t * 18 + j] *= inv;
    }
    __syncthreads();
    for (int idx = t; idx < S_ * 64; idx += 256) {
        int i = idx >> 6, d = idx & 63;
        float s = 0.f;
        #pragma unroll
        for (int j = 0; j < S_; ++j) s = fmaf(att[i * 18 + j], vs[j * 65 + d], s);
        obuf[(size_t)(bq + i) * D_ + h * 64 + d] = s;
    }
}

// ===========================================================================
// Residual + LN -> abuf (verified)
// ===========================================================================
__global__ __launch_bounds__(256)
void resln_kernel(const float* __restrict__ z0, const float* __restrict__ projb,
                  const float* __restrict__ ln_g, const float* __restrict__ ln_b,
                  float* __restrict__ abuf)
{
    __shared__ float sm[8];
    const int r = blockIdx.x, t = threadIdx.x;
    float v[3];
    #pragma unroll
    for (int p = 0; p < 3; ++p) {
        int d = t + 256 * p;
        v[p] = z0[(size_t)r * D_ + d] + projb[(size_t)r * D_ + d];
    }
    float sum = 0.f, ss = 0.f;
    #pragma unroll
    for (int p = 0; p < 3; ++p) { sum += v[p]; ss += v[p] * v[p]; }
    #pragma unroll
    for (int o = 32; o; o >>= 1) { sum += __shfl_down(sum, o); ss += __shfl_down(ss, o); }
    int wid = t >> 6, la = t & 63;
    if (la == 0) { sm[wid * 2] = sum; sm[wid * 2 + 1] = ss; }
    __syncthreads();
    sum = sm[0] + sm[2] + sm[4] + sm[6];
    ss  = sm[1] + sm[3] + sm[5] + sm[7];
    float m = sum * (1.0f / D_), rstd = rsqrtf(ss * (1.0f / D_) - m * m + 1e-5f);
    #pragma unroll
    for (int p = 0; p < 3; ++p) {
        int d = t + 256 * p;
        abuf[(size_t)r * D_ + d] = (v[p] - m) * rstd * ln_g[d] + ln_b[d];
    }
}

// ===========================================================================
// Layer-1 attention, query row 0 only; writes compact o1c[b][768]
// ===========================================================================
__global__ __launch_bounds__(128)
void attn1r0_kernel(const float* __restrict__ qkvb, float* __restrict__ o1c)
{
    __shared__ float q0[64], kv[S_][65], vv[S_][64], p[S_], red[2];
    const int bh = blockIdx.x, b = bh / H_, h = bh % H_;
    const int t = threadIdx.x;
    const size_t rowbase = (size_t)(b * S_) * (3 * D_) + h * 64;

    for (int idx = t; idx < S_ * 64; idx += 128) {
        int s = idx >> 6, d = idx & 63;
        kv[s][d] = qkvb[rowbase + (size_t)s * (3 * D_) + D_ + d];
        vv[s][d] = qkvb[rowbase + (size_t)s * (3 * D_) + 2 * D_ + d];
    }
    if (t < 64) q0[t] = qkvb[rowbase + t];
    __syncthreads();
    if (t < S_) {
        float sdot = 0.f;
        #pragma unroll
        for (int d = 0; d < 64; ++d) sdot = fmaf(q0[d], kv[t][d], sdot);
        p[t] = sdot * 0.125f;
    }
    __syncthreads();
    if (t == 0) {
        float mx = -1e30f;
        for (int j = 0; j < S_; ++j) mx = fmaxf(mx, p[j]);
        red[0] = mx;
    }
    __syncthreads();
    if (t < S_) p[t] = expf(p[t] - red[0]);
    __syncthreads();
    if (t == 0) {
        float s = 0.f;
        for (int j = 0; j < S_; ++j) s += p[j];
        red[1] = 1.0f / s;
    }
    __syncthreads();
    if (t < 64) {
        float s = 0.f;
        #pragma unroll
        for (int j = 0; j < S_; ++j) s = fmaf(p[j], vv[j][t], s);
        o1c[(size_t)b * D_ + h * 64 + t] = s * red[1];
    }
}

// ===========================================================================
// Layer-1 projection, M=16: projc[16][768]
// ===========================================================================
__global__ __launch_bounds__(256)
void proj1c_kernel(const float* __restrict__ A,   // o1c [16][768]
                   const float* __restrict__ W,   // Wo1 [768][768]
                   const float* __restrict__ bias,
                   float* __restrict__ C)         // projc [16][768]
{
    __shared__ __align__(16) char SB[20480];
    char* AhB = SB;            // [16][64] bf16 = 2KB
    char* AlB = SB + 2048;
    char* WhB = SB + 4096;     // [64][64] = 8KB
    char* WlB = SB + 12288;

    const int t  = threadIdx.x;
    const int n0 = blockIdx.x * 64;

    const int ar = t >> 4;            // 0..15
    const int ac = (t & 15) * 4;      // col group of 4
    const int sr = t >> 2;            // 0..63 (W row)
    const int sc = (t & 3) * 16;

    const int wv = t >> 6, la = t & 63;
    const int fr = la & 15, fq = la >> 4;

    f32x4 acc = {0.f, 0.f, 0.f, 0.f};

    float4 pa = *(const float4*)(A + (size_t)ar * D_ + ac);
    float4 pw[4];
    #pragma unroll
    for (int q = 0; q < 4; ++q)
        pw[q] = *(const float4*)(W + (size_t)(n0 + sr) * D_ + sc + q * 4);

    for (int kt = 0; kt < 12; ++kt) {
        __syncthreads();
        {
            ushort4 hh, ll;
            split4(pa, hh, ll);
            int byte = (ar * 128 + ac * 2) ^ ((ar & 7) << 4);
            *(ushort4*)(AhB + byte) = hh;
            *(ushort4*)(AlB + byte) = ll;
            ushort4 whh[4], wll[4];
            #pragma unroll
            for (int q = 0; q < 4; ++q) split4(pw[q], whh[q], wll[q]);
            int wb0 = (sr * 128 + sc * 2) ^ ((sr & 7) << 4);
            int wb1 = (sr * 128 + sc * 2 + 16) ^ ((sr & 7) << 4);
            *(ushort4*)(WhB + wb0)     = whh[0];
            *(ushort4*)(WhB + wb0 + 8) = whh[1];
            *(ushort4*)(WhB + wb1)     = whh[2];
            *(ushort4*)(WhB + wb1 + 8) = whh[3];
            *(ushort4*)(WlB + wb0)     = wll[0];
            *(ushort4*)(WlB + wb0 + 8) = wll[1];
            *(ushort4*)(WlB + wb1)     = wll[2];
            *(ushort4*)(WlB + wb1 + 8) = wll[3];
        }
        __syncthreads();
        if (kt < 11) {
            pa = *(const float4*)(A + (size_t)ar * D_ + (kt + 1) * 64 + ac);
            #pragma unroll
            for (int q = 0; q < 4; ++q)
                pw[q] = *(const float4*)(W + (size_t)(n0 + sr) * D_ + (kt + 1) * 64 + sc + q * 4);
        }
        #pragma unroll
        for (int ks = 0; ks < 2; ++ks) {
            int kb = ks * 64 + fq * 16;
            int abyte = (fr * 128 + kb) ^ ((fr & 7) << 4);
            bf16x8 ah = *(const bf16x8*)(AhB + abyte);
            bf16x8 al = *(const bf16x8*)(AlB + abyte);
            int r = wv * 16 + fr;
            int wbyte = (r * 128 + kb) ^ ((r & 7) << 4);
            bf16x8 bh = *(const bf16x8*)(WhB + wbyte);
            bf16x8 bl = *(const bf16x8*)(WlB + wbyte);
            acc = __builtin_amdgcn_mfma_f32_16x16x32_bf16(ah, bh, acc, 0, 0, 0);
            acc = __builtin_amdgcn_mfma_f32_16x16x32_bf16(ah, bl, acc, 0, 0, 0);
            acc = __builtin_amdgcn_mfma_f32_16x16x32_bf16(al, bh, acc, 0, 0, 0);
        }
    }

    #pragma unroll
    for (int j = 0; j < 4; ++j) {
        int m = fq * 4 + j;              // 0..15
        int n = n0 + wv * 16 + fr;
        C[(size_t)m * D_ + n] = acc[j] + bias[n];
    }
}

// ===========================================================================
// Final output: out[b] = LN(z0[b*17] + projc[b])
// ===========================================================================
__global__ __launch_bounds__(256)
void outln_kernel(const float* __restrict__ z0, const float* __restrict__ projc,
                  const float* __restrict__ ln_g, const float* __restrict__ ln_b,
                  float* __restrict__ out)
{
    __shared__ float sm[8];
    const int b = blockIdx.x, t = threadIdx.x;
    float v[3];
    #pragma unroll
    for (int p = 0; p < 3; ++p) {
        int d = t + 256 * p;
        v[p] = z0[((size_t)b * S_) * D_ + d] + projc[(size_t)b * D_ + d];
    }
    float sum = 0.f, ss = 0.f;
    #pragma unroll
    for (int p = 0; p < 3; ++p) { sum += v[p]; ss += v[p] * v[p]; }
    #pragma unroll
    for (int o = 32; o; o >>= 1) { sum += __shfl_down(sum, o); ss += __shfl_down(ss, o); }
    int wid = t >> 6, la = t & 63;
    if (la == 0) { sm[wid * 2] = sum; sm[wid * 2 + 1] = ss; }
    __syncthreads();
    sum = sm[0] + sm[2] + sm[4] + sm[6];
    ss  = sm[1] + sm[3] + sm[5] + sm[7];
    float m = sum * (1.0f / D_), rstd = rsqrtf(ss * (1.0f / D_) - m * m + 1e-5f);
    #pragma unroll
    for (int p = 0; p < 3; ++p) {
        int d = t + 256 * p;
        out[(size_t)b * D_ + d] = (v[p] - m) * rstd * ln_g[d] + ln_b[d];
    }
}

// ---------------------------------------------------------------------------
extern "C" void kernel_launch(void* const* d_in, const int* in_sizes, int n_in,
                              void* d_out, int out_size, void* d_ws, size_t ws_size,
                              hipStream_t stream)
{
    const float* x     = (const float*)d_in[0];
    const float* cls   = (const float*)d_in[1];
    const float* ln_g  = (const float*)d_in[2];
    const float* ln_b  = (const float*)d_in[3];
    const float* gln_g = (const float*)d_in[4];
    const float* gln_b = (const float*)d_in[5];
    const float* gW1   = (const float*)d_in[6];
    const float* gb1   = (const float*)d_in[7];
    const float* gW2   = (const float*)d_in[8];
    const float* gb2   = (const float*)d_in[9];
    const float* Wqkv  = (const float*)d_in[10];
    const float* bqkv  = (const float*)d_in[11];
    const float* Wo    = (const float*)d_in[12];
    const float* bo    = (const float*)d_in[13];
    float* out = (float*)d_out;

    float* ws    = (float*)d_ws;
    float* wbuf  = ws;                          // 65536
    float* z0    = ws + BN_;                    // 208896
    float* abuf  = z0 + (size_t)M_ * D_;        // 208896
    float* qkvb  = abuf + (size_t)M_ * D_;      // 626688
    float* obuf  = qkvb + (size_t)M_ * 3 * D_;  // 208896 (layer1: o1c = first 16*768)
    float* projb = obuf + (size_t)M_ * D_;      // 208896 (layer1: projc = first 16*768)
    float* topv  = projb + (size_t)M_ * D_;     // 256
    int*   topi  = (int*)(topv + 256);          // 256

    gate_kernel<<<BN_ / 128, 256, 0, stream>>>(x, gln_g, gln_b, gW1, gb1, gW2, gb2, wbuf);
    topk_kernel<<<B_, 256, 0, stream>>>(wbuf, topv, topi);
    build_kernel<<<M_, 256, 0, stream>>>(x, cls, ln_g, ln_b, topv, topi, z0);

    // layer 0 (full)
    gemm_mfma<<<dim3(5, 36), 256, 0, stream>>>(z0, Wqkv, bqkv, qkvb, 3 * D_);
    attn_kernel<<<B_ * H_, 256, 0, stream>>>(qkvb, obuf);
    gemm_mfma<<<dim3(5, 12), 256, 0, stream>>>(obuf, Wo, bo, projb, D_);
    resln_kernel<<<M_, 256, 0, stream>>>(z0, projb, ln_g, ln_b, abuf);

    // layer 1 (trimmed to row s=0 outputs)
    gemm_mfma<<<dim3(5, 36), 256, 0, stream>>>(abuf, Wqkv + (size_t)3 * D_ * D_,
                                               bqkv + 3 * D_, qkvb, 3 * D_);
    attn1r0_kernel<<<B_ * H_, 128, 0, stream>>>(qkvb, obuf);
    proj1c_kernel<<<12, 256, 0, stream>>>(obuf, Wo + (size_t)D_ * D_, bo + D_, projb);
    outln_kernel<<<B_, 256, 0, stream>>>(z0, projb, ln_g, ln_b, out);
}